// Round 5
// baseline (754.291 us; speedup 1.0000x reference)
//
#include <hip/hip_runtime.h>

// ---- problem constants ----
#define Hdim   3584
#define NH     28
#define NKV    4
#define HD     128
#define Sq     2048
#define NQKV   4608          // 3584 q + 512 k + 512 v
#define KD     3584          // inner dim of both GEMMs
#define NIT    1372          // attn work items: 952 split halves + 420 whole

typedef unsigned short u16;
typedef _Float16 f16;
typedef _Float16 f16x8 __attribute__((ext_vector_type(8)));     // MFMA A/B operand (4 VGPRs)
typedef unsigned short u16x8 __attribute__((ext_vector_type(8)));
typedef float f32x4 __attribute__((ext_vector_type(4)));        // MFMA C/D operand

__device__ __forceinline__ u16 f2h(float x) { f16 h = (f16)x; return __builtin_bit_cast(u16, h); }
__device__ __forceinline__ float h2f(u16 b) { return (float)__builtin_bit_cast(f16, b); }
__device__ __forceinline__ void split2(float x, u16& hi, u16& lo) {
    hi = f2h(x);
    lo = f2h(x - h2f(hi));   // combined ~22-bit mantissa
}

// async global->LDS, 16B per lane; LDS dest = wave-uniform base + lane*16
#define GLL16(gp, lp) __builtin_amdgcn_global_load_lds( \
    (__attribute__((address_space(1))) void*)(gp),      \
    (__attribute__((address_space(3))) void*)(lp), 16, 0, 0)

// ---- fp32 -> fp16, 8 elems/thread ----
__global__ void k_cvt(const float* __restrict__ x, u16* __restrict__ yh, int n8) {
    int i = blockIdx.x * 256 + threadIdx.x;
    if (i >= n8) return;
    const float4* p = (const float4*)(x + (size_t)i * 8);
    float4 a = p[0], b = p[1];
    float v[8] = {a.x, a.y, a.z, a.w, b.x, b.y, b.z, b.w};
    u16x8 h;
#pragma unroll
    for (int j = 0; j < 8; ++j) h[j] = f2h(v[j]);
    *(u16x8*)(yh + (size_t)i * 8) = h;
}

// ---- concat biases (q|k|v) ----
__global__ void k_bias(const float* __restrict__ bq, const float* __restrict__ bk,
                       const float* __restrict__ bv, float* __restrict__ out) {
    int i = blockIdx.x * 256 + threadIdx.x;
    if (i >= NQKV) return;
    out[i] = (i < 3584) ? bq[i] : (i < 4096 ? bk[i - 3584] : bv[i - 4096]);
}

// ---- AWQ int4 dequant -> W (dout x KD) fp16, row-major over output cols ----
__global__ void k_dequant(const int* __restrict__ qw, const int* __restrict__ qz,
                          const float* __restrict__ sc, u16* __restrict__ W, int dout) {
    int idx = blockIdx.x * 256 + threadIdx.x;
    int rb = idx % 448;            // 448 = 3584/8 row-blocks
    int c  = idx / 448;
    if (c >= dout) return;
    int w8 = dout >> 3;
    int j  = c >> 3, sh = (c & 7) << 2;
    int g  = rb >> 4;              // (rb*8)/128  (G=128)
    int z  = (qz[(size_t)g * w8 + j] >> sh) & 15;
    float s = sc[(size_t)g * dout + c];
    int r0 = rb * 8;
    u16x8 v;
#pragma unroll
    for (int i = 0; i < 8; ++i) {
        int w = (qw[(size_t)(r0 + i) * w8 + j] >> sh) & 15;
        v[i] = f2h((float)(w - z) * s);
    }
    *(u16x8*)(W + (size_t)c * KD + r0) = v;
}

// ---- fp16 MFMA GEMM (m97-style + T2 XOR-swizzle + T1 XCD swizzle) ----
// T2: 128B LDS row stride = 32 banks -> chunk16B ^= row&7 on BOTH sides
// (pre-swizzled global source for global_load_lds + swizzled ds_read).
// Measured R4: SQ_LDS_BANK_CONFLICT = 0.
// T1: linear dispatch spreads same-A-panel blocks over all 8 XCDs
// ((x+4y)&7 covers all) -> 8x A re-fetch through L3. Bijective chunk remap
// confines each A-panel to ~1 XCD (per-z nwg = 576/448, both %8==0).
__global__ __launch_bounds__(256) void k_gemm_f16(const u16* __restrict__ A,
                                                  const u16* __restrict__ B,
                                                  const float* __restrict__ bias,
                                                  float* __restrict__ C,
                                                  float* __restrict__ Cp,
                                                  int M, int N, int K) {
    __shared__ __attribute__((aligned(16))) u16 Ash[128 * 64];
    __shared__ __attribute__((aligned(16))) u16 Bsh[128 * 64];
    int tid = threadIdx.x;
    unsigned nwg = gridDim.x * gridDim.y;
    unsigned lin = blockIdx.x + gridDim.x * blockIdx.y;
    if ((nwg & 7) == 0) lin = (lin & 7) * (nwg >> 3) + (lin >> 3);   // XCD chunking
    int m0 = (int)(lin / gridDim.x) * 128, n0 = (int)(lin % gridDim.x) * 128;
    int klen = K / gridDim.z;
    int kbeg = blockIdx.z * klen, kend = kbeg + klen;
    int wave = tid >> 6, lane = tid & 63;
    int l16 = lane & 15, quad = lane >> 4;
    int wr = wave >> 1, wc = wave & 1;
    int lrow = lane >> 3, lcol = lane & 7;      // staging: 8 rows x 8 chunks(16B)
    int scol = lcol ^ lrow;                     // pre-swizzled source chunk
    int sw = l16 & 7;                           // read-side swizzle key (= row&7)

    f32x4 acc[4][4];
    f32x4 zero4 = {0.f, 0.f, 0.f, 0.f};
#pragma unroll
    for (int i = 0; i < 4; ++i)
#pragma unroll
        for (int j = 0; j < 4; ++j) acc[i][j] = zero4;

    for (int kk = kbeg; kk < kend; kk += 64) {
        __syncthreads();                         // WAR: prior ds_reads done
#pragma unroll
        for (int j = 0; j < 4; ++j) {
            int rbase = wave * 32 + j * 8;       // wave-uniform, 8-aligned
            size_t ga = (size_t)(m0 + rbase + lrow) * K + kk + scol * 8;
            size_t gb = (size_t)(n0 + rbase + lrow) * K + kk + scol * 8;
            GLL16(A + ga, &Ash[rbase * 64]);
            GLL16(B + gb, &Bsh[rbase * 64]);
        }
        __syncthreads();                         // vmcnt(0) drain -> data visible
#pragma unroll
        for (int kc = 0; kc < 2; ++kc) {
            f16x8 af[4], bv[4];
#pragma unroll
            for (int i = 0; i < 4; ++i)
                af[i] = *(const f16x8*)&Ash[(wr * 64 + i * 16 + l16) * 64
                                            + (((kc * 4 + quad) ^ sw) << 3)];
#pragma unroll
            for (int j = 0; j < 4; ++j)
                bv[j] = *(const f16x8*)&Bsh[(wc * 64 + j * 16 + l16) * 64
                                            + (((kc * 4 + quad) ^ sw) << 3)];
#pragma unroll
            for (int i = 0; i < 4; ++i)
#pragma unroll
                for (int j = 0; j < 4; ++j)
                    acc[i][j] = __builtin_amdgcn_mfma_f32_16x16x32_f16(af[i], bv[j], acc[i][j], 0, 0, 0);
        }
    }
    float* dst = (blockIdx.z == 0) ? C : Cp;
    bool addb = (bias != nullptr) && (blockIdx.z == 0);
#pragma unroll
    for (int i = 0; i < 4; ++i)
#pragma unroll
        for (int r = 0; r < 4; ++r) {
            int row = m0 + wr * 64 + i * 16 + quad * 4 + r;
#pragma unroll
            for (int j = 0; j < 4; ++j) {
                int col = n0 + wc * 64 + j * 16 + l16;
                float v = acc[i][j][r];
                if (addb) v += bias[col];
                dst[(size_t)row * N + col] = v;
            }
        }
}

// ---- out += partial (fp32, float4) ----
__global__ void k_reduce(float* __restrict__ out, const float* __restrict__ part, int n4) {
    int i = blockIdx.x * 256 + threadIdx.x;
    if (i >= n4) return;
    float4 a = ((const float4*)out)[i];
    float4 b = ((const float4*)part)[i];
    a.x += b.x; a.y += b.y; a.z += b.z; a.w += b.w;
    ((float4*)out)[i] = a;
}

// ---- RoPE (fp64 angles) -> Qh/Ql (S,3584), Kh (S,512) fp16 ----
// Q is pre-scaled by 1/sqrt(HD) * log2(e): attention scores then come out of
// QK^T directly in log2 domain (softmax via exp2 = raw v_exp_f32).
// Yp: optional split-K partial of Y (added in fp32 before rotation)
__global__ void k_rope2(const float* __restrict__ Y, const float* __restrict__ Yp,
                        const int* __restrict__ pos,
                        u16* __restrict__ Qh, u16* __restrict__ Ql,
                        u16* __restrict__ Kh) {
    __shared__ double finv[64];
    int tid = threadIdx.x;
    if (tid < 64)   // inv_freq = theta^(-i/64) = 2^(-i*log2(1e6)/64)
        finv[tid] = exp2(-0.3114307588956902 * (double)tid);
    __syncthreads();
    int s = blockIdx.x;
    double p = (double)pos[s];
    const float* y  = Y + (size_t)s * NQKV;
    const float* yp = Yp ? (Yp + (size_t)s * NQKV) : nullptr;
    const float QSCALE = 0.1275174313f;     // (1/sqrt(128)) * log2(e)
    for (int idx = tid; idx < 4096; idx += 256) {
        int d = idx & 127;
        int i = d & 63;
        double ang = p * finv[i];
        double n = rint(ang * 0.15915494309189535);          // /(2*pi)
        float r = (float)fma(-6.283185307179586, n, ang);    // range-reduced angle
        float sn, cs;
        __sincosf(r, &sn, &cs);
        int idx2 = (d < 64) ? idx + 64 : idx - 64;
        float v  = y[idx];
        float v2 = y[idx2];
        if (yp) { v += yp[idx]; v2 += yp[idx2]; }
        float o  = (d < 64) ? (v * cs - v2 * sn) : (v * cs + v2 * sn);
        if (idx < 3584) {
            u16 hh, ll;
            split2(o * QSCALE, hh, ll);
            Qh[(size_t)s * 3584 + idx] = hh;
            Ql[(size_t)s * 3584 + idx] = ll;
        } else {
            Kh[(size_t)s * 512 + (idx - 3584)] = f2h(o);
        }
    }
}

// ---- transpose V section of Y: (S x 512) fp32 -> Vt (512 x S) fp16 ----
// Yp: optional split-K partial of Y (added in fp32 before convert)
__global__ __launch_bounds__(256) void k_vtrans(const float* __restrict__ Y,
                                                const float* __restrict__ Yp,
                                                u16* __restrict__ Vt) {
    __shared__ __attribute__((aligned(16))) u16 T[64][72];
    int s0 = blockIdx.x * 64, d0 = blockIdx.y * 64;
    int tid = threadIdx.x;
#pragma unroll
    for (int t = 0; t < 16; ++t) {
        int idx = tid + t * 256;
        int r = idx >> 6, c = idx & 63;
        size_t goff = (size_t)(s0 + r) * NQKV + 4096 + d0 + c;
        float val = Y[goff];
        if (Yp) val += Yp[goff];
        T[c][r] = f2h(val);
    }
    __syncthreads();
#pragma unroll
    for (int t = 0; t < 2; ++t) {
        int cc = tid + t * 256;
        int dr = cc >> 3, s8 = (cc & 7) << 3;
        *(u16x8*)(Vt + (size_t)(d0 + dr) * Sq + s0 + s8) = *(const u16x8*)&T[dr][s8];
    }
}

// ---- flash attention fp16: persistent blocks, dynamic LPT queue + key-split ----
// Load-balance fix: makespan was pinned by the 28 qt=31 items (32 kt-tiles)
// while shorter items drained -> ~half the kernel ran on <30 of 256 CUs.
// Items with qt >= 15 are split into two key-range halves (952 sub-items,
// len 8..16) + 420 whole items (qt <= 14). Halves write unnormalized flash
// partials (O,m,l fp32) to workspace; second-arriving half merges
// (device-scope fence + atomic flag per G16) and writes AO.
// LDS: XOR-swizzled power-of-2 tiles (chunk16B ^= row&7), 40960 B total.
// Softmax in log2 domain (Q pre-scaled at RoPE) + T13 defer-max + T5 setprio.
// NOTE R3 lesson: __launch_bounds__(256,4) forced VGPR 132->64 => full spill
// (hbm_bytes 5.7e7 -> 6.5e8). Natural allocation is mandatory here.
__global__ __launch_bounds__(256) void k_attn(const u16* __restrict__ Qh,
                                              const u16* __restrict__ Ql,
                                              const u16* __restrict__ Kh,
                                              const u16* __restrict__ Vt,
                                              u16* __restrict__ AO,
                                              int* __restrict__ ctr,
                                              int* __restrict__ flags,
                                              float* __restrict__ PO,
                                              float* __restrict__ Pml) {
    __shared__ __attribute__((aligned(16))) u16 Ks[64][128];   // 16384 B, swizzled
    __shared__ __attribute__((aligned(16))) u16 Vs[128][64];   // 16384 B, swizzled
    __shared__ __attribute__((aligned(16))) u16 Ps[4][16][64]; //  8192 B, swizzled

    int tid = threadIdx.x;
    int wave = tid >> 6, lane = tid & 63, l16 = lane & 15, quad = lane >> 4;
    int sw = l16 & 7;                       // read-side swizzle key (= row&7)

    for (;;) {
        __syncthreads();                   // all waves done with prior item
        if (tid == 0) *(int*)&Ks[0][0] = atomicAdd(ctr, 1);
        __syncthreads();
        int item = *(const int*)&Ks[0][0];
        if (item >= NIT) break;            // block-uniform exit
        int qt, h, kbeg, kend, pair = -1, slot = 0;
        if (item < 952) {                  // split halves, qt 31..15 (LPT-ish)
            int p = item >> 1;
            int half = item & 1;
            qt = 31 - p / 28; h = p % 28;
            int hi = (qt + 1) >> 1;
            kbeg = half ? hi : 0;
            kend = half ? qt + 1 : hi;
            pair = p; slot = item;         // slot = p*2+half
        } else {                           // whole items, qt 14..0
            int j = item - 952;
            qt = 14 - j / 28; h = j % 28;
            kbeg = 0; kend = qt + 1;
        }
        int q0 = qt * 64;
        int kvh = h / 7;                   // NH/NKV = 7
        __syncthreads();                   // item slot read by all before staging

        const u16* Kbase = Kh + kvh * HD;                  // row stride 512
        const u16* Vbase = Vt + (size_t)(kvh * HD) * Sq;   // row stride Sq

        // Q fragments hi/lo direct from global (A-layout: m=l16, k=quad*8+j)
        f16x8 qfh[4], qfl[4];
        {
            size_t qoff = (size_t)(q0 + wave * 16 + l16) * Hdim + h * HD + quad * 8;
#pragma unroll
            for (int kc = 0; kc < 4; ++kc) {
                qfh[kc] = *(const f16x8*)(Qh + qoff + kc * 32);
                qfl[kc] = *(const f16x8*)(Ql + qoff + kc * 32);
            }
        }

        // initial staging of tile kbeg (swizzled writes)
        int kb0 = kbeg * 64;
#pragma unroll
        for (int t = 0; t < 4; ++t) {
            int c = tid + t * 256;
            int row = c >> 4, ch = (c & 15) ^ (row & 7);
            *(u16x8*)&Ks[row][ch << 3] = *(const u16x8*)(Kbase + (size_t)(kb0 + row) * 512 + ((c & 15) << 3));
        }
#pragma unroll
        for (int t = 0; t < 4; ++t) {
            int c = tid + t * 256;
            int d = c >> 3, ch = (c & 7) ^ (d & 7);
            *(u16x8*)&Vs[d][ch << 3] = *(const u16x8*)(Vbase + (size_t)d * Sq + kb0 + ((c & 7) << 3));
        }
        __syncthreads();

        f32x4 O[8];
        f32x4 zero4 = {0.f, 0.f, 0.f, 0.f};
#pragma unroll
        for (int t = 0; t < 8; ++t) O[t] = zero4;
        float mrow[4], lrow[4];
#pragma unroll
        for (int r = 0; r < 4; ++r) { mrow[r] = -1e30f; lrow[r] = 0.f; }

        for (int kt = kbeg; kt < kend; ++kt) {
            int k0 = kt * 64;
            int kn = ((kt + 1 < kend) ? kt + 1 : kt) * 64;   // clamped prefetch base

            // ---- issue next-tile loads into registers (latency overlapped) ----
            u16x8 nk[4], nv[4];
#pragma unroll
            for (int t = 0; t < 4; ++t) {
                int c = tid + t * 256;
                nk[t] = *(const u16x8*)(Kbase + (size_t)(kn + (c >> 4)) * 512 + ((c & 15) << 3));
                nv[t] = *(const u16x8*)(Vbase + (size_t)(c >> 3) * Sq + kn + ((c & 7) << 3));
            }

            // ---- compute current tile from LDS (log2-domain scores) ----
            f32x4 sa[4];                       // S = Q K^T, 2-term split
            __builtin_amdgcn_s_setprio(1);
#pragma unroll
            for (int ct = 0; ct < 4; ++ct) {
                f32x4 z = zero4;
#pragma unroll
                for (int kc = 0; kc < 4; ++kc) {
                    f16x8 b = *(const f16x8*)&Ks[ct * 16 + l16][(((kc * 4 + quad) ^ sw)) << 3];
                    z = __builtin_amdgcn_mfma_f32_16x16x32_f16(qfh[kc], b, z, 0, 0, 0);
                    z = __builtin_amdgcn_mfma_f32_16x16x32_f16(qfl[kc], b, z, 0, 0, 0);
                }
                sa[ct] = z;
            }
            __builtin_amdgcn_s_setprio(0);
            if (kt == qt) {
#pragma unroll
                for (int ct = 0; ct < 4; ++ct)
#pragma unroll
                    for (int r = 0; r < 4; ++r)
                        if (k0 + ct * 16 + l16 > q0 + wave * 16 + quad * 4 + r) sa[ct][r] = -1e30f;
            }
            // row max of this tile
            float pmax[4];
#pragma unroll
            for (int r = 0; r < 4; ++r) {
                float mx = fmaxf(fmaxf(sa[0][r], sa[1][r]), fmaxf(sa[2][r], sa[3][r]));
#pragma unroll
                for (int off = 1; off < 16; off <<= 1)
                    mx = fmaxf(mx, __shfl_xor(mx, off, 64));
                pmax[r] = mx;
            }
            // T13 defer-max: skip rescale while max growth <= 8 (P <= 2^8)
            bool keep = (pmax[0] <= mrow[0] + 8.f) && (pmax[1] <= mrow[1] + 8.f) &&
                        (pmax[2] <= mrow[2] + 8.f) && (pmax[3] <= mrow[3] + 8.f);
            if (!__all(keep)) {
#pragma unroll
                for (int r = 0; r < 4; ++r) {
                    float mnew = fmaxf(mrow[r], pmax[r]);
                    float alpha = exp2f(mrow[r] - mnew);
                    mrow[r] = mnew;
                    lrow[r] *= alpha;
#pragma unroll
                    for (int ct = 0; ct < 8; ++ct) O[ct][r] *= alpha;
                }
            }
            float rs[4] = {0.f, 0.f, 0.f, 0.f};
#pragma unroll
            for (int ct = 0; ct < 4; ++ct)
#pragma unroll
                for (int r = 0; r < 4; ++r) {
                    float p = exp2f(sa[ct][r] - mrow[r]);
                    rs[r] += p;
                    // swizzled Ps write: chunk ^= row&7, row = quad*4+r
                    Ps[wave][quad * 4 + r][(ct * 16 + l16) ^ (((quad * 4 + r) & 7) << 3)] = f2h(p);
                }
#pragma unroll
            for (int r = 0; r < 4; ++r) {
#pragma unroll
                for (int off = 1; off < 16; off <<= 1)
                    rs[r] += __shfl_xor(rs[r], off, 64);
                lrow[r] += rs[r];
            }
            __builtin_amdgcn_s_setprio(1);
#pragma unroll
            for (int kc = 0; kc < 2; ++kc) {   // PV from LDS (Ps wave-private)
                f16x8 a = *(const f16x8*)&Ps[wave][l16][(((kc * 4 + quad) ^ sw)) << 3];
#pragma unroll
                for (int ct = 0; ct < 8; ++ct) {
                    f16x8 b = *(const f16x8*)&Vs[ct * 16 + l16][(((kc * 4 + quad) ^ sw)) << 3];
                    O[ct] = __builtin_amdgcn_mfma_f32_16x16x32_f16(a, b, O[ct], 0, 0, 0);
                }
            }
            __builtin_amdgcn_s_setprio(0);

            // ---- commit prefetched tile to LDS (swizzled) ----
            __syncthreads();                   // all waves done reading Ks/Vs
#pragma unroll
            for (int t = 0; t < 4; ++t) {
                int c = tid + t * 256;
                int row = c >> 4, chk = ((c & 15) ^ (row & 7));
                int d = c >> 3, chv = ((c & 7) ^ (d & 7));
                *(u16x8*)&Ks[row][chk << 3] = nk[t];
                *(u16x8*)&Vs[d][chv << 3]   = nv[t];
            }
            __syncthreads();                   // staged data visible
        }

        if (pair < 0) {
            // whole item: normalize and write output directly
#pragma unroll
            for (int r = 0; r < 4; ++r) {
                float inv = 1.f / lrow[r];
                int row = q0 + wave * 16 + quad * 4 + r;
#pragma unroll
                for (int ct = 0; ct < 8; ++ct)
                    AO[(size_t)row * 3584 + h * HD + ct * 16 + l16] = f2h(O[ct][r] * inv);
            }
        } else {
            // split half: write unnormalized partial (O, m, l)
            float* po = PO + (size_t)slot * (64 * 128);
#pragma unroll
            for (int r = 0; r < 4; ++r) {
                int wrow = wave * 16 + quad * 4 + r;
#pragma unroll
                for (int ct = 0; ct < 8; ++ct)
                    po[wrow * 128 + ct * 16 + l16] = O[ct][r];
                if (l16 == 0) {
                    Pml[slot * 128 + wrow * 2]     = mrow[r];
                    Pml[slot * 128 + wrow * 2 + 1] = lrow[r];
                }
            }
            __syncthreads();
            __threadfence();                    // release partial to device scope
            if (tid == 0) *(int*)&Vs[0][0] = atomicAdd(&flags[pair], 1);
            __syncthreads();
            int arrived = *(const int*)&Vs[0][0];
            if (arrived == 1) {                 // second finisher merges
                __threadfence();                // acquire partner's writes
                const float* poA = PO + (size_t)(pair * 2) * (64 * 128);
                const float* poB = poA + 64 * 128;
                const float* mlA = Pml + (size_t)(pair * 2) * 128;
                const float* mlB = mlA + 128;
                for (int e = tid; e < 64 * 128; e += 256) {
                    int row = e >> 7, col = e & 127;
                    float mA = mlA[row * 2], lA = mlA[row * 2 + 1];
                    float mB = mlB[row * 2], lB = mlB[row * 2 + 1];
                    float ms = fmaxf(mA, mB);
                    float aA = exp2f(mA - ms), aB = exp2f(mB - ms);
                    float l  = lA * aA + lB * aB;
                    float o  = (poA[e] * aA + poB[e] * aB) / l;
                    AO[(size_t)(q0 + row) * 3584 + h * HD + col] = f2h(o);
                }
            }
        }
    }
}

extern "C" void kernel_launch(void* const* d_in, const int* in_sizes, int n_in,
                              void* d_out, int out_size, void* d_ws, size_t ws_size,
                              hipStream_t stream) {
    (void)in_sizes; (void)n_in; (void)out_size;
    const float* hidden = (const float*)d_in[0];
    const int*   pos    = (const int*)d_in[1];
    const int*   qw_q = (const int*)d_in[2];
    const int*   qz_q = (const int*)d_in[3];
    const float* sc_q = (const float*)d_in[4];
    const float* b_q  = (const float*)d_in[5];
    const int*   qw_k = (const int*)d_in[6];
    const int*   qz_k = (const int*)d_in[7];
    const float* sc_k = (const float*)d_in[8];
    const float* b_k  = (const float*)d_in[9];
    const int*   qw_v = (const int*)d_in[10];
    const int*   qz_v = (const int*)d_in[11];
    const float* sc_v = (const float*)d_in[12];
    const float* b_v  = (const float*)d_in[13];
    const int*   qw_o = (const int*)d_in[14];
    const int*   qz_o = (const int*)d_in[15];
    const float* sc_o = (const float*)d_in[16];
    float* out = (float*)d_out;

    char* base = (char*)d_ws;
    size_t off = 0;
    auto alloc = [&](size_t bytes) {
        char* p = base + off;
        off += (bytes + 255) & ~(size_t)255;
        return p;
    };
    u16* Wh = (u16*)alloc((size_t)NQKV * KD * 2);   // 33.0 MB (reused for W_o)
    u16* Xh = (u16*)alloc((size_t)Sq * Hdim * 2);   // 14.7 MB (reused as Qh, then partial)
    u16* Xl = (u16*)alloc((size_t)Sq * Hdim * 2);   // 14.7 MB (Ql, then partial)
    float* Y = (float*)alloc((size_t)Sq * NQKV * 4);// 37.7 MB (reused for AO)
    u16* Khb = (u16*)alloc((size_t)Sq * 512 * 2);   //  2.1 MB
    u16* Vt  = (u16*)alloc((size_t)512 * Sq * 2);   //  2.1 MB
    float* biasc = (float*)alloc(NQKV * 4);
    int*   ctr   = (int*)alloc(4096);               // [0]=attn queue, [16..]=pair flags
    // split-K partial for GEMM1 (live GEMM1 -> rope/vtrans); gated on ws_size.
    // Dead after vtrans -> reused as attn split partials (PO 31.2MB + Pml 0.5MB).
    float* Part1 = (float*)alloc((size_t)Sq * NQKV * 4);   // 37.7 MB
    bool deep = (off <= ws_size);
    u16* Qhb = Xh;                 // Xh dead after GEMM1
    u16* Qlb = Xl;
    u16* AO  = (u16*)Y;            // Y dead after rope/vtrans
    u16* Wo  = Wh;                 // Wh dead after GEMM1
    float* Part = (float*)Xh;      // Xh+Xl contiguous = 29.4 MB, dead after attn
    int*   flags = ctr + 16;       // 476 ints, zeroed with ctr
    float* PO  = Part1;                          // 952 x 64 x 128 f32
    float* Pml = Part1 + (size_t)952 * 64 * 128; // 952 x 64 x {m,l}

    hipMemsetAsync(ctr, 0, 4096, stream);           // ws is re-poisoned each call
    k_cvt<<<3584, 256, 0, stream>>>(hidden, Xh, (Sq * Hdim) / 8);
    k_bias<<<18, 256, 0, stream>>>(b_q, b_k, b_v, biasc);
    k_dequant<<<(3584 * 448) / 256, 256, 0, stream>>>(qw_q, qz_q, sc_q, Wh, 3584);
    k_dequant<<<(512 * 448) / 256, 256, 0, stream>>>(qw_k, qz_k, sc_k, Wh + (size_t)3584 * KD, 512);
    k_dequant<<<(512 * 448) / 256, 256, 0, stream>>>(qw_v, qz_v, sc_v, Wh + (size_t)4096 * KD, 512);
    // GEMM1: split-K=2 -> 1152 blocks = 4.5/CU; partial folded into rope/vtrans.
    if (deep) {
        k_gemm_f16<<<dim3(NQKV / 128, Sq / 128, 2), 256, 0, stream>>>(Xh, Wh, biasc, Y, Part1, Sq, NQKV, KD);
    } else {
        k_gemm_f16<<<dim3(NQKV / 128, Sq / 128, 1), 256, 0, stream>>>(Xh, Wh, biasc, Y, nullptr, Sq, NQKV, KD);
    }
    k_rope2<<<Sq, 256, 0, stream>>>(Y, deep ? Part1 : nullptr, pos, Qhb, Qlb, Khb);
    k_vtrans<<<dim3(Sq / 64, 512 / 64), 256, 0, stream>>>(Y, deep ? Part1 : nullptr, Vt);
    k_dequant<<<(3584 * 448) / 256, 256, 0, stream>>>(qw_o, qz_o, sc_o, Wo, 3584);
    k_attn<<<dim3(1024), 256, 0, stream>>>(Qhb, Qlb, Khb, Vt, AO, ctr, flags, PO, Pml);
    k_gemm_f16<<<dim3(Hdim / 128, Sq / 128, 2), 256, 0, stream>>>(AO, Wo, nullptr, out, Part, Sq, Hdim, KD);
    k_reduce<<<(Sq * Hdim / 4 + 255) / 256, 256, 0, stream>>>(out, Part, Sq * Hdim / 4);
}

// Round 6
// 581.238 us; speedup vs baseline: 1.2977x; 1.2977x over previous
//
#include <hip/hip_runtime.h>

// ---- problem constants ----
#define Hdim   3584
#define NH     28
#define NKV    4
#define HD     128
#define Sq     2048
#define NQKV   4608          // 3584 q + 512 k + 512 v
#define KD     3584          // inner dim of both GEMMs
#define NSPL   952           // split halves (476 pairs, qt 31..15)
#define NPAIR  476

typedef unsigned short u16;
typedef _Float16 f16;
typedef _Float16 f16x8 __attribute__((ext_vector_type(8)));     // MFMA A/B operand (4 VGPRs)
typedef unsigned short u16x8 __attribute__((ext_vector_type(8)));
typedef unsigned short u16x4 __attribute__((ext_vector_type(4)));
typedef float f32x4 __attribute__((ext_vector_type(4)));        // MFMA C/D operand

__device__ __forceinline__ u16 f2h(float x) { f16 h = (f16)x; return __builtin_bit_cast(u16, h); }
__device__ __forceinline__ float h2f(u16 b) { return (float)__builtin_bit_cast(f16, b); }
__device__ __forceinline__ void split2(float x, u16& hi, u16& lo) {
    hi = f2h(x);
    lo = f2h(x - h2f(hi));   // combined ~22-bit mantissa
}

// async global->LDS, 16B per lane; LDS dest = wave-uniform base + lane*16
#define GLL16(gp, lp) __builtin_amdgcn_global_load_lds( \
    (__attribute__((address_space(1))) void*)(gp),      \
    (__attribute__((address_space(3))) void*)(lp), 16, 0, 0)

// ---- fp32 -> fp16, 8 elems/thread ----
__global__ void k_cvt(const float* __restrict__ x, u16* __restrict__ yh, int n8) {
    int i = blockIdx.x * 256 + threadIdx.x;
    if (i >= n8) return;
    const float4* p = (const float4*)(x + (size_t)i * 8);
    float4 a = p[0], b = p[1];
    float v[8] = {a.x, a.y, a.z, a.w, b.x, b.y, b.z, b.w};
    u16x8 h;
#pragma unroll
    for (int j = 0; j < 8; ++j) h[j] = f2h(v[j]);
    *(u16x8*)(yh + (size_t)i * 8) = h;
}

// ---- concat biases (q|k|v) ----
__global__ void k_bias(const float* __restrict__ bq, const float* __restrict__ bk,
                       const float* __restrict__ bv, float* __restrict__ out) {
    int i = blockIdx.x * 256 + threadIdx.x;
    if (i >= NQKV) return;
    out[i] = (i < 3584) ? bq[i] : (i < 4096 ? bk[i - 3584] : bv[i - 4096]);
}

// ---- AWQ int4 dequant -> W (dout x KD) fp16, row-major over output cols ----
__global__ void k_dequant(const int* __restrict__ qw, const int* __restrict__ qz,
                          const float* __restrict__ sc, u16* __restrict__ W, int dout) {
    int idx = blockIdx.x * 256 + threadIdx.x;
    int rb = idx % 448;            // 448 = 3584/8 row-blocks
    int c  = idx / 448;
    if (c >= dout) return;
    int w8 = dout >> 3;
    int j  = c >> 3, sh = (c & 7) << 2;
    int g  = rb >> 4;              // (rb*8)/128  (G=128)
    int z  = (qz[(size_t)g * w8 + j] >> sh) & 15;
    float s = sc[(size_t)g * dout + c];
    int r0 = rb * 8;
    u16x8 v;
#pragma unroll
    for (int i = 0; i < 8; ++i) {
        int w = (qw[(size_t)(r0 + i) * w8 + j] >> sh) & 15;
        v[i] = f2h((float)(w - z) * s);
    }
    *(u16x8*)(W + (size_t)c * KD + r0) = v;
}

// ---- fp16 MFMA GEMM (m97-style + T2 XOR-swizzle + T1 XCD swizzle) ----
// T2: 128B LDS row stride = 32 banks -> chunk16B ^= row&7 on BOTH sides
// (pre-swizzled global source for global_load_lds + swizzled ds_read).
// Measured R4: SQ_LDS_BANK_CONFLICT = 0.
__global__ __launch_bounds__(256) void k_gemm_f16(const u16* __restrict__ A,
                                                  const u16* __restrict__ B,
                                                  const float* __restrict__ bias,
                                                  float* __restrict__ C,
                                                  float* __restrict__ Cp,
                                                  int M, int N, int K) {
    __shared__ __attribute__((aligned(16))) u16 Ash[128 * 64];
    __shared__ __attribute__((aligned(16))) u16 Bsh[128 * 64];
    int tid = threadIdx.x;
    unsigned nwg = gridDim.x * gridDim.y;
    unsigned lin = blockIdx.x + gridDim.x * blockIdx.y;
    if ((nwg & 7) == 0) lin = (lin & 7) * (nwg >> 3) + (lin >> 3);   // XCD chunking
    int m0 = (int)(lin / gridDim.x) * 128, n0 = (int)(lin % gridDim.x) * 128;
    int klen = K / gridDim.z;
    int kbeg = blockIdx.z * klen, kend = kbeg + klen;
    int wave = tid >> 6, lane = tid & 63;
    int l16 = lane & 15, quad = lane >> 4;
    int wr = wave >> 1, wc = wave & 1;
    int lrow = lane >> 3, lcol = lane & 7;      // staging: 8 rows x 8 chunks(16B)
    int scol = lcol ^ lrow;                     // pre-swizzled source chunk
    int sw = l16 & 7;                           // read-side swizzle key (= row&7)

    f32x4 acc[4][4];
    f32x4 zero4 = {0.f, 0.f, 0.f, 0.f};
#pragma unroll
    for (int i = 0; i < 4; ++i)
#pragma unroll
        for (int j = 0; j < 4; ++j) acc[i][j] = zero4;

    for (int kk = kbeg; kk < kend; kk += 64) {
        __syncthreads();                         // WAR: prior ds_reads done
#pragma unroll
        for (int j = 0; j < 4; ++j) {
            int rbase = wave * 32 + j * 8;       // wave-uniform, 8-aligned
            size_t ga = (size_t)(m0 + rbase + lrow) * K + kk + scol * 8;
            size_t gb = (size_t)(n0 + rbase + lrow) * K + kk + scol * 8;
            GLL16(A + ga, &Ash[rbase * 64]);
            GLL16(B + gb, &Bsh[rbase * 64]);
        }
        __syncthreads();                         // vmcnt(0) drain -> data visible
#pragma unroll
        for (int kc = 0; kc < 2; ++kc) {
            f16x8 af[4], bv[4];
#pragma unroll
            for (int i = 0; i < 4; ++i)
                af[i] = *(const f16x8*)&Ash[(wr * 64 + i * 16 + l16) * 64
                                            + (((kc * 4 + quad) ^ sw) << 3)];
#pragma unroll
            for (int j = 0; j < 4; ++j)
                bv[j] = *(const f16x8*)&Bsh[(wc * 64 + j * 16 + l16) * 64
                                            + (((kc * 4 + quad) ^ sw) << 3)];
#pragma unroll
            for (int i = 0; i < 4; ++i)
#pragma unroll
                for (int j = 0; j < 4; ++j)
                    acc[i][j] = __builtin_amdgcn_mfma_f32_16x16x32_f16(af[i], bv[j], acc[i][j], 0, 0, 0);
        }
    }
    float* dst = (blockIdx.z == 0) ? C : Cp;
    bool addb = (bias != nullptr) && (blockIdx.z == 0);
#pragma unroll
    for (int i = 0; i < 4; ++i)
#pragma unroll
        for (int r = 0; r < 4; ++r) {
            int row = m0 + wr * 64 + i * 16 + quad * 4 + r;
#pragma unroll
            for (int j = 0; j < 4; ++j) {
                int col = n0 + wc * 64 + j * 16 + l16;
                float v = acc[i][j][r];
                if (addb) v += bias[col];
                dst[(size_t)row * N + col] = v;
            }
        }
}

// ---- out += partial (fp32, float4) ----
__global__ void k_reduce(float* __restrict__ out, const float* __restrict__ part, int n4) {
    int i = blockIdx.x * 256 + threadIdx.x;
    if (i >= n4) return;
    float4 a = ((const float4*)out)[i];
    float4 b = ((const float4*)part)[i];
    a.x += b.x; a.y += b.y; a.z += b.z; a.w += b.w;
    ((float4*)out)[i] = a;
}

// ---- RoPE (fp64 angles) -> Qh/Ql (S,3584), Kh (S,512) fp16 ----
// Q is pre-scaled by 1/sqrt(HD) * log2(e): scores come out of QK^T in log2
// domain (softmax via exp2). Yp: optional split-K partial (added pre-rotate).
__global__ void k_rope2(const float* __restrict__ Y, const float* __restrict__ Yp,
                        const int* __restrict__ pos,
                        u16* __restrict__ Qh, u16* __restrict__ Ql,
                        u16* __restrict__ Kh) {
    __shared__ double finv[64];
    int tid = threadIdx.x;
    if (tid < 64)   // inv_freq = theta^(-i/64) = 2^(-i*log2(1e6)/64)
        finv[tid] = exp2(-0.3114307588956902 * (double)tid);
    __syncthreads();
    int s = blockIdx.x;
    double p = (double)pos[s];
    const float* y  = Y + (size_t)s * NQKV;
    const float* yp = Yp ? (Yp + (size_t)s * NQKV) : nullptr;
    const float QSCALE = 0.1275174313f;     // (1/sqrt(128)) * log2(e)
    for (int idx = tid; idx < 4096; idx += 256) {
        int d = idx & 127;
        int i = d & 63;
        double ang = p * finv[i];
        double n = rint(ang * 0.15915494309189535);          // /(2*pi)
        float r = (float)fma(-6.283185307179586, n, ang);    // range-reduced angle
        float sn, cs;
        __sincosf(r, &sn, &cs);
        int idx2 = (d < 64) ? idx + 64 : idx - 64;
        float v  = y[idx];
        float v2 = y[idx2];
        if (yp) { v += yp[idx]; v2 += yp[idx2]; }
        float o  = (d < 64) ? (v * cs - v2 * sn) : (v * cs + v2 * sn);
        if (idx < 3584) {
            u16 hh, ll;
            split2(o * QSCALE, hh, ll);
            Qh[(size_t)s * 3584 + idx] = hh;
            Ql[(size_t)s * 3584 + idx] = ll;
        } else {
            Kh[(size_t)s * 512 + (idx - 3584)] = f2h(o);
        }
    }
}

// ---- transpose V section of Y: (S x 512) fp32 -> Vt (512 x S) fp16 ----
__global__ __launch_bounds__(256) void k_vtrans(const float* __restrict__ Y,
                                                const float* __restrict__ Yp,
                                                u16* __restrict__ Vt) {
    __shared__ __attribute__((aligned(16))) u16 T[64][72];
    int s0 = blockIdx.x * 64, d0 = blockIdx.y * 64;
    int tid = threadIdx.x;
#pragma unroll
    for (int t = 0; t < 16; ++t) {
        int idx = tid + t * 256;
        int r = idx >> 6, c = idx & 63;
        size_t goff = (size_t)(s0 + r) * NQKV + 4096 + d0 + c;
        float val = Y[goff];
        if (Yp) val += Yp[goff];
        T[c][r] = f2h(val);
    }
    __syncthreads();
#pragma unroll
    for (int t = 0; t < 2; ++t) {
        int cc = tid + t * 256;
        int dr = cc >> 3, s8 = (cc & 7) << 3;
        *(u16x8*)(Vt + (size_t)(d0 + dr) * Sq + s0 + s8) = *(const u16x8*)&T[dr][s8];
    }
}

// ---- flash attention fp16: persistent blocks, LPT queue + key-split ----
// Split items (qt>=15) write unnormalized partials (O,m,l) with PLAIN stores;
// the merge runs in a separate k_amerge kernel (dispatch boundary = free
// device-wide visibility). R5 lesson: in-kernel cross-block merge needed
// __threadfence() per half => 952 XCD-L2 writeback/invalidates serialized the
// memory system (attn 115->299us, FETCH +27MB from L2 churn). Never again.
// LDS: XOR-swizzled power-of-2 tiles (chunk16B ^= row&7), 40960 B total.
// Softmax in log2 domain + T13 defer-max + T5 setprio.
// R3 lesson: no min-waves clamp (forcing VGPR down spills everything).
__global__ __launch_bounds__(256) void k_attn(const u16* __restrict__ Qh,
                                              const u16* __restrict__ Ql,
                                              const u16* __restrict__ Kh,
                                              const u16* __restrict__ Vt,
                                              u16* __restrict__ AO,
                                              int* __restrict__ ctr,
                                              float* __restrict__ PO,
                                              float* __restrict__ Pml,
                                              int nsplit, int nit) {
    __shared__ __attribute__((aligned(16))) u16 Ks[64][128];   // 16384 B, swizzled
    __shared__ __attribute__((aligned(16))) u16 Vs[128][64];   // 16384 B, swizzled
    __shared__ __attribute__((aligned(16))) u16 Ps[4][16][64]; //  8192 B, swizzled

    int tid = threadIdx.x;
    int wave = tid >> 6, lane = tid & 63, l16 = lane & 15, quad = lane >> 4;
    int sw = l16 & 7;                       // read-side swizzle key (= row&7)

    for (;;) {
        __syncthreads();                   // all waves done with prior item
        if (tid == 0) *(int*)&Ks[0][0] = atomicAdd(ctr, 1);
        __syncthreads();
        int item = *(const int*)&Ks[0][0];
        if (item >= nit) break;            // block-uniform exit
        int qt, h, kbeg, kend, slot = -1;
        if (item < nsplit) {               // split halves, qt 31..15 (LPT)
            int p = item >> 1, half = item & 1;
            qt = 31 - p / 28; h = p % 28;
            int hi = (qt + 1) >> 1;
            kbeg = half ? hi : 0;
            kend = half ? qt + 1 : hi;
            slot = item;
        } else {                           // whole items
            int j = item - nsplit;
            int qbase = nsplit ? 14 : 31;
            qt = qbase - j / 28; h = j % 28;
            kbeg = 0; kend = qt + 1;
        }
        int q0 = qt * 64;
        int kvh = h / 7;                   // NH/NKV = 7
        __syncthreads();                   // item slot read by all before staging

        const u16* Kbase = Kh + kvh * HD;                  // row stride 512
        const u16* Vbase = Vt + (size_t)(kvh * HD) * Sq;   // row stride Sq

        // Q fragments hi/lo direct from global (A-layout: m=l16, k=quad*8+j)
        f16x8 qfh[4], qfl[4];
        {
            size_t qoff = (size_t)(q0 + wave * 16 + l16) * Hdim + h * HD + quad * 8;
#pragma unroll
            for (int kc = 0; kc < 4; ++kc) {
                qfh[kc] = *(const f16x8*)(Qh + qoff + kc * 32);
                qfl[kc] = *(const f16x8*)(Ql + qoff + kc * 32);
            }
        }

        // initial staging of tile kbeg (swizzled writes)
        int kb0 = kbeg * 64;
#pragma unroll
        for (int t = 0; t < 4; ++t) {
            int c = tid + t * 256;
            int row = c >> 4, ch = (c & 15) ^ (row & 7);
            *(u16x8*)&Ks[row][ch << 3] = *(const u16x8*)(Kbase + (size_t)(kb0 + row) * 512 + ((c & 15) << 3));
        }
#pragma unroll
        for (int t = 0; t < 4; ++t) {
            int c = tid + t * 256;
            int d = c >> 3, ch = (c & 7) ^ (d & 7);
            *(u16x8*)&Vs[d][ch << 3] = *(const u16x8*)(Vbase + (size_t)d * Sq + kb0 + ((c & 7) << 3));
        }
        __syncthreads();

        f32x4 O[8];
        f32x4 zero4 = {0.f, 0.f, 0.f, 0.f};
#pragma unroll
        for (int t = 0; t < 8; ++t) O[t] = zero4;
        float mrow[4], lrow[4];
#pragma unroll
        for (int r = 0; r < 4; ++r) { mrow[r] = -1e30f; lrow[r] = 0.f; }

        for (int kt = kbeg; kt < kend; ++kt) {
            int k0 = kt * 64;
            int kn = ((kt + 1 < kend) ? kt + 1 : kt) * 64;   // clamped prefetch base

            // ---- issue next-tile loads into registers (latency overlapped) ----
            u16x8 nk[4], nv[4];
#pragma unroll
            for (int t = 0; t < 4; ++t) {
                int c = tid + t * 256;
                nk[t] = *(const u16x8*)(Kbase + (size_t)(kn + (c >> 4)) * 512 + ((c & 15) << 3));
                nv[t] = *(const u16x8*)(Vbase + (size_t)(c >> 3) * Sq + kn + ((c & 7) << 3));
            }

            // ---- compute current tile from LDS (log2-domain scores) ----
            f32x4 sa[4];                       // S = Q K^T, 2-term split
            __builtin_amdgcn_s_setprio(1);
#pragma unroll
            for (int ct = 0; ct < 4; ++ct) {
                f32x4 z = zero4;
#pragma unroll
                for (int kc = 0; kc < 4; ++kc) {
                    f16x8 b = *(const f16x8*)&Ks[ct * 16 + l16][(((kc * 4 + quad) ^ sw)) << 3];
                    z = __builtin_amdgcn_mfma_f32_16x16x32_f16(qfh[kc], b, z, 0, 0, 0);
                    z = __builtin_amdgcn_mfma_f32_16x16x32_f16(qfl[kc], b, z, 0, 0, 0);
                }
                sa[ct] = z;
            }
            __builtin_amdgcn_s_setprio(0);
            if (kt == qt) {
#pragma unroll
                for (int ct = 0; ct < 4; ++ct)
#pragma unroll
                    for (int r = 0; r < 4; ++r)
                        if (k0 + ct * 16 + l16 > q0 + wave * 16 + quad * 4 + r) sa[ct][r] = -1e30f;
            }
            // row max of this tile
            float pmax[4];
#pragma unroll
            for (int r = 0; r < 4; ++r) {
                float mx = fmaxf(fmaxf(sa[0][r], sa[1][r]), fmaxf(sa[2][r], sa[3][r]));
#pragma unroll
                for (int off = 1; off < 16; off <<= 1)
                    mx = fmaxf(mx, __shfl_xor(mx, off, 64));
                pmax[r] = mx;
            }
            // T13 defer-max: skip rescale while max growth <= 8 (P <= 2^8)
            bool keep = (pmax[0] <= mrow[0] + 8.f) && (pmax[1] <= mrow[1] + 8.f) &&
                        (pmax[2] <= mrow[2] + 8.f) && (pmax[3] <= mrow[3] + 8.f);
            if (!__all(keep)) {
#pragma unroll
                for (int r = 0; r < 4; ++r) {
                    float mnew = fmaxf(mrow[r], pmax[r]);
                    float alpha = exp2f(mrow[r] - mnew);
                    mrow[r] = mnew;
                    lrow[r] *= alpha;
#pragma unroll
                    for (int ct = 0; ct < 8; ++ct) O[ct][r] *= alpha;
                }
            }
            float rs[4] = {0.f, 0.f, 0.f, 0.f};
#pragma unroll
            for (int ct = 0; ct < 4; ++ct)
#pragma unroll
                for (int r = 0; r < 4; ++r) {
                    float p = exp2f(sa[ct][r] - mrow[r]);
                    rs[r] += p;
                    // swizzled Ps write: chunk ^= row&7, row = quad*4+r
                    Ps[wave][quad * 4 + r][(ct * 16 + l16) ^ (((quad * 4 + r) & 7) << 3)] = f2h(p);
                }
#pragma unroll
            for (int r = 0; r < 4; ++r) {
#pragma unroll
                for (int off = 1; off < 16; off <<= 1)
                    rs[r] += __shfl_xor(rs[r], off, 64);
                lrow[r] += rs[r];
            }
            __builtin_amdgcn_s_setprio(1);
#pragma unroll
            for (int kc = 0; kc < 2; ++kc) {   // PV from LDS (Ps wave-private)
                f16x8 a = *(const f16x8*)&Ps[wave][l16][(((kc * 4 + quad) ^ sw)) << 3];
#pragma unroll
                for (int ct = 0; ct < 8; ++ct) {
                    f16x8 b = *(const f16x8*)&Vs[ct * 16 + l16][(((kc * 4 + quad) ^ sw)) << 3];
                    O[ct] = __builtin_amdgcn_mfma_f32_16x16x32_f16(a, b, O[ct], 0, 0, 0);
                }
            }
            __builtin_amdgcn_s_setprio(0);

            // ---- commit prefetched tile to LDS (swizzled) ----
            __syncthreads();                   // all waves done reading Ks/Vs
#pragma unroll
            for (int t = 0; t < 4; ++t) {
                int c = tid + t * 256;
                int row = c >> 4, chk = ((c & 15) ^ (row & 7));
                int d = c >> 3, chv = ((c & 7) ^ (d & 7));
                *(u16x8*)&Ks[row][chk << 3] = nk[t];
                *(u16x8*)&Vs[d][chv << 3]   = nv[t];
            }
            __syncthreads();                   // staged data visible
        }

        if (slot < 0) {
            // whole item: normalize and write output directly
#pragma unroll
            for (int r = 0; r < 4; ++r) {
                float inv = 1.f / lrow[r];
                int row = q0 + wave * 16 + quad * 4 + r;
#pragma unroll
                for (int ct = 0; ct < 8; ++ct)
                    AO[(size_t)row * 3584 + h * HD + ct * 16 + l16] = f2h(O[ct][r] * inv);
            }
        } else {
            // split half: plain-store unnormalized partial (O, m, l)
            float* po = PO + (size_t)slot * (64 * 128);
#pragma unroll
            for (int r = 0; r < 4; ++r) {
                int wrow = wave * 16 + quad * 4 + r;
#pragma unroll
                for (int ct = 0; ct < 8; ++ct)
                    po[wrow * 128 + ct * 16 + l16] = O[ct][r];
                if (l16 == 0) {
                    Pml[slot * 128 + wrow * 2]     = mrow[r];
                    Pml[slot * 128 + wrow * 2 + 1] = lrow[r];
                }
            }
        }
    }
}

// ---- merge split-pair flash partials -> AO (one block per pair) ----
__global__ __launch_bounds__(256) void k_amerge(const float* __restrict__ PO,
                                                const float* __restrict__ Pml,
                                                u16* __restrict__ AO) {
    int p = blockIdx.x;
    int qt = 31 - p / 28, h = p % 28, q0 = qt * 64;
    const float* poA = PO + (size_t)(p * 2) * (64 * 128);
    const float* poB = poA + 64 * 128;
    const float* mlA = Pml + (size_t)(p * 2) * 128;
    const float* mlB = mlA + 128;
    int tid = threadIdx.x;
    for (int i = tid; i < 2048; i += 256) {      // 64 rows x 32 float4
        int row = i >> 5, c4 = (i & 31) << 2;
        float mA = mlA[row * 2], lA = mlA[row * 2 + 1];
        float mB = mlB[row * 2], lB = mlB[row * 2 + 1];
        float ms = fmaxf(mA, mB);
        float aA = exp2f(mA - ms), aB = exp2f(mB - ms);
        float inv = 1.f / (lA * aA + lB * aB);
        float4 oA = *(const float4*)(poA + row * 128 + c4);
        float4 oB = *(const float4*)(poB + row * 128 + c4);
        u16x4 o;
        o[0] = f2h((oA.x * aA + oB.x * aB) * inv);
        o[1] = f2h((oA.y * aA + oB.y * aB) * inv);
        o[2] = f2h((oA.z * aA + oB.z * aB) * inv);
        o[3] = f2h((oA.w * aA + oB.w * aB) * inv);
        *(u16x4*)(AO + (size_t)(q0 + row) * 3584 + h * HD + c4) = o;
    }
}

extern "C" void kernel_launch(void* const* d_in, const int* in_sizes, int n_in,
                              void* d_out, int out_size, void* d_ws, size_t ws_size,
                              hipStream_t stream) {
    (void)in_sizes; (void)n_in; (void)out_size;
    const float* hidden = (const float*)d_in[0];
    const int*   pos    = (const int*)d_in[1];
    const int*   qw_q = (const int*)d_in[2];
    const int*   qz_q = (const int*)d_in[3];
    const float* sc_q = (const float*)d_in[4];
    const float* b_q  = (const float*)d_in[5];
    const int*   qw_k = (const int*)d_in[6];
    const int*   qz_k = (const int*)d_in[7];
    const float* sc_k = (const float*)d_in[8];
    const float* b_k  = (const float*)d_in[9];
    const int*   qw_v = (const int*)d_in[10];
    const int*   qz_v = (const int*)d_in[11];
    const float* sc_v = (const float*)d_in[12];
    const float* b_v  = (const float*)d_in[13];
    const int*   qw_o = (const int*)d_in[14];
    const int*   qz_o = (const int*)d_in[15];
    const float* sc_o = (const float*)d_in[16];
    float* out = (float*)d_out;

    char* base = (char*)d_ws;
    size_t off = 0;
    auto alloc = [&](size_t bytes) {
        char* p = base + off;
        off += (bytes + 255) & ~(size_t)255;
        return p;
    };
    u16* Wh = (u16*)alloc((size_t)NQKV * KD * 2);   // 33.0 MB (reused for W_o)
    u16* Xh = (u16*)alloc((size_t)Sq * Hdim * 2);   // 14.7 MB (reused as Qh, then partial)
    u16* Xl = (u16*)alloc((size_t)Sq * Hdim * 2);   // 14.7 MB (Ql, then partial)
    float* Y = (float*)alloc((size_t)Sq * NQKV * 4);// 37.7 MB (reused for AO)
    u16* Khb = (u16*)alloc((size_t)Sq * 512 * 2);   //  2.1 MB
    u16* Vt  = (u16*)alloc((size_t)512 * Sq * 2);   //  2.1 MB
    float* biasc = (float*)alloc(NQKV * 4);
    int*   ctr   = (int*)alloc(4096);               // attn work-queue counter
    // split-K partial for GEMM1 (live GEMM1 -> rope/vtrans); gated on ws_size.
    // Dead after vtrans -> reused as attn split partials (PO 31.2MB + Pml 0.5MB).
    float* Part1 = (float*)alloc((size_t)Sq * NQKV * 4);   // 37.7 MB
    bool deep = (off <= ws_size);
    u16* Qhb = Xh;                 // Xh dead after GEMM1
    u16* Qlb = Xl;
    u16* AO  = (u16*)Y;            // Y dead after rope/vtrans
    u16* Wo  = Wh;                 // Wh dead after GEMM1
    float* Part = (float*)Xh;      // Xh+Xl contiguous = 29.4 MB, dead after attn
    float* PO  = Part1;                          // 952 x 64 x 128 f32
    float* Pml = Part1 + (size_t)NSPL * 64 * 128; // 952 x 64 x {m,l}

    hipMemsetAsync(ctr, 0, 4096, stream);           // ws is re-poisoned each call
    k_cvt<<<3584, 256, 0, stream>>>(hidden, Xh, (Sq * Hdim) / 8);
    k_bias<<<18, 256, 0, stream>>>(b_q, b_k, b_v, biasc);
    k_dequant<<<(3584 * 448) / 256, 256, 0, stream>>>(qw_q, qz_q, sc_q, Wh, 3584);
    k_dequant<<<(512 * 448) / 256, 256, 0, stream>>>(qw_k, qz_k, sc_k, Wh + (size_t)3584 * KD, 512);
    k_dequant<<<(512 * 448) / 256, 256, 0, stream>>>(qw_v, qz_v, sc_v, Wh + (size_t)4096 * KD, 512);
    // GEMM1: split-K=2 -> 1152 blocks = 4.5/CU; partial folded into rope/vtrans.
    if (deep) {
        k_gemm_f16<<<dim3(NQKV / 128, Sq / 128, 2), 256, 0, stream>>>(Xh, Wh, biasc, Y, Part1, Sq, NQKV, KD);
    } else {
        k_gemm_f16<<<dim3(NQKV / 128, Sq / 128, 1), 256, 0, stream>>>(Xh, Wh, biasc, Y, nullptr, Sq, NQKV, KD);
    }
    k_rope2<<<Sq, 256, 0, stream>>>(Y, deep ? Part1 : nullptr, pos, Qhb, Qlb, Khb);
    k_vtrans<<<dim3(Sq / 64, 512 / 64), 256, 0, stream>>>(Y, deep ? Part1 : nullptr, Vt);
    k_dequant<<<(3584 * 448) / 256, 256, 0, stream>>>(qw_o, qz_o, sc_o, Wo, 3584);
    if (deep) {
        // key-split attn (952 halves + 420 whole) + separate merge pass
        k_attn<<<dim3(1024), 256, 0, stream>>>(Qhb, Qlb, Khb, Vt, AO, ctr, PO, Pml, NSPL, NSPL + 420);
        k_amerge<<<dim3(NPAIR), 256, 0, stream>>>(PO, Pml, AO);
    } else {
        k_attn<<<dim3(1024), 256, 0, stream>>>(Qhb, Qlb, Khb, Vt, AO, ctr, nullptr, nullptr, 0, 896);
    }
    k_gemm_f16<<<dim3(Hdim / 128, Sq / 128, 2), 256, 0, stream>>>(AO, Wo, nullptr, out, Part, Sq, Hdim, KD);
    k_reduce<<<(Sq * Hdim / 4 + 255) / 256, 256, 0, stream>>>(out, Part, Sq * Hdim / 4);
}

// Round 7
// 463.361 us; speedup vs baseline: 1.6279x; 1.2544x over previous
//
#include <hip/hip_runtime.h>

// ---- problem constants ----
#define Hdim   3584
#define NH     28
#define NKV    4
#define HD     128
#define Sq     2048
#define NQKV   4608          // 3584 q + 512 k + 512 v
#define KD     3584          // inner dim of both GEMMs

typedef unsigned short u16;
typedef unsigned int   u32;
typedef _Float16 f16;
typedef _Float16 f16x8 __attribute__((ext_vector_type(8)));     // MFMA A/B operand (4 VGPRs)
typedef unsigned short u16x8 __attribute__((ext_vector_type(8)));
typedef float f32x4 __attribute__((ext_vector_type(4)));        // MFMA C/D operand

__device__ __forceinline__ u16 f2h(float x) { f16 h = (f16)x; return __builtin_bit_cast(u16, h); }
__device__ __forceinline__ float h2f(u16 b) { return (float)__builtin_bit_cast(f16, b); }
__device__ __forceinline__ void split2(float x, u16& hi, u16& lo) {
    hi = f2h(x);
    lo = f2h(x - h2f(hi));   // combined ~22-bit mantissa
}

// async global->LDS, 16B per lane; LDS dest = wave-uniform base + lane*16
#define GLL16(gp, lp) __builtin_amdgcn_global_load_lds( \
    (__attribute__((address_space(1))) void*)(gp),      \
    (__attribute__((address_space(3))) void*)(lp), 16, 0, 0)

// ---- fp32 -> fp16, 8 elems/thread ----
__global__ void k_cvt(const float* __restrict__ x, u16* __restrict__ yh, int n8) {
    int i = blockIdx.x * 256 + threadIdx.x;
    if (i >= n8) return;
    const float4* p = (const float4*)(x + (size_t)i * 8);
    float4 a = p[0], b = p[1];
    float v[8] = {a.x, a.y, a.z, a.w, b.x, b.y, b.z, b.w};
    u16x8 h;
#pragma unroll
    for (int j = 0; j < 8; ++j) h[j] = f2h(v[j]);
    *(u16x8*)(yh + (size_t)i * 8) = h;
}

// ---- concat biases (q|k|v) ----
__global__ void k_bias(const float* __restrict__ bq, const float* __restrict__ bk,
                       const float* __restrict__ bv, float* __restrict__ out) {
    int i = blockIdx.x * 256 + threadIdx.x;
    if (i >= NQKV) return;
    out[i] = (i < 3584) ? bq[i] : (i < 4096 ? bk[i - 3584] : bv[i - 4096]);
}

// ---- AWQ int4 dequant -> W (dout x KD) fp16 --- tiled LDS transpose ----
// R6 post-mortem: the old per-thread layout read qw at stride 1792B ->
// 64 transactions per load instruction, 12.8M scattered 4B requests/launch
// (transaction-rate bound, est. 50-90us each for the two 3584-col launches).
// New: 64-row x 64-col tile per block; qw words staged coalesced into LDS
// (32B runs), one scale+zero per output chunk, u16x8 coalesced writes.
__global__ __launch_bounds__(256) void k_dequant(const int* __restrict__ qw,
                                                 const int* __restrict__ qz,
                                                 const float* __restrict__ sc,
                                                 u16* __restrict__ W, int dout) {
    __shared__ u32 L[64][9];       // 64 rows x 8 words (+1 pad: breaks bank resonance)
    __shared__ float scl[64];
    __shared__ u32 zq[8];
    int tid = threadIdx.x;
    int w8 = dout >> 3;
    int c0 = blockIdx.x * 64, j0 = blockIdx.x * 8;
    int r0 = blockIdx.y * 64, g = r0 >> 7;       // G=128, r0%128 in {0,64} -> uniform
#pragma unroll
    for (int t = 0; t < 2; ++t) {
        int u = tid + t * 256;
        int rr = u >> 3, jj = u & 7;             // coalesced: 8 consecutive words/row
        L[rr][jj] = (u32)qw[(size_t)(r0 + rr) * w8 + j0 + jj];
    }
    if (tid < 64) scl[tid] = sc[(size_t)g * dout + c0 + tid];
    if (tid < 8)  zq[tid]  = (u32)qz[(size_t)g * w8 + j0 + tid];
    __syncthreads();
#pragma unroll
    for (int t = 0; t < 2; ++t) {
        int u = tid + t * 256;
        int lc = u >> 3, r8 = (u & 7) << 3;      // chunk: col c0+lc, rows r0+r8..+7
        int sh = (lc & 7) << 2, jc = lc >> 3;
        int z = (int)((zq[jc] >> sh) & 15u);
        float s = scl[lc];
        u16x8 v;
#pragma unroll
        for (int i = 0; i < 8; ++i) {
            int w = (int)((L[r8 + i][jc] >> sh) & 15u);
            v[i] = f2h((float)(w - z) * s);
        }
        *(u16x8*)(W + (size_t)(c0 + lc) * KD + r0 + r8) = v;
    }
}

// ---- fp16 MFMA GEMM (m97-style + T2 XOR-swizzle): C = A @ B^T + bias ----
// T2: 128B LDS row stride = 32 banks -> chunk16B ^= row&7 on BOTH sides
// (pre-swizzled global source for global_load_lds + swizzled ds_read).
// Measured R4: SQ_LDS_BANK_CONFLICT = 0.
// R6 lesson: XCD-chunked blockIdx remap INCREASED FETCH 124->183MB (+5us):
// linear order already time-shares one A-panel across all XCDs via L3;
// chunking put 8 A-panels in flight -> L3 thrash. Keep linear.
__global__ __launch_bounds__(256) void k_gemm_f16(const u16* __restrict__ A,
                                                  const u16* __restrict__ B,
                                                  const float* __restrict__ bias,
                                                  float* __restrict__ C,
                                                  float* __restrict__ Cp,
                                                  int M, int N, int K) {
    __shared__ __attribute__((aligned(16))) u16 Ash[128 * 64];
    __shared__ __attribute__((aligned(16))) u16 Bsh[128 * 64];
    int tid = threadIdx.x;
    int m0 = blockIdx.y * 128, n0 = blockIdx.x * 128;
    int klen = K / gridDim.z;
    int kbeg = blockIdx.z * klen, kend = kbeg + klen;
    int wave = tid >> 6, lane = tid & 63;
    int l16 = lane & 15, quad = lane >> 4;
    int wr = wave >> 1, wc = wave & 1;
    int lrow = lane >> 3, lcol = lane & 7;      // staging: 8 rows x 8 chunks(16B)
    int scol = lcol ^ lrow;                     // pre-swizzled source chunk
    int sw = l16 & 7;                           // read-side swizzle key (= row&7)

    f32x4 acc[4][4];
    f32x4 zero4 = {0.f, 0.f, 0.f, 0.f};
#pragma unroll
    for (int i = 0; i < 4; ++i)
#pragma unroll
        for (int j = 0; j < 4; ++j) acc[i][j] = zero4;

    for (int kk = kbeg; kk < kend; kk += 64) {
        __syncthreads();                         // WAR: prior ds_reads done
#pragma unroll
        for (int j = 0; j < 4; ++j) {
            int rbase = wave * 32 + j * 8;       // wave-uniform, 8-aligned
            size_t ga = (size_t)(m0 + rbase + lrow) * K + kk + scol * 8;
            size_t gb = (size_t)(n0 + rbase + lrow) * K + kk + scol * 8;
            GLL16(A + ga, &Ash[rbase * 64]);
            GLL16(B + gb, &Bsh[rbase * 64]);
        }
        __syncthreads();                         // vmcnt(0) drain -> data visible
#pragma unroll
        for (int kc = 0; kc < 2; ++kc) {
            f16x8 af[4], bv[4];
#pragma unroll
            for (int i = 0; i < 4; ++i)
                af[i] = *(const f16x8*)&Ash[(wr * 64 + i * 16 + l16) * 64
                                            + (((kc * 4 + quad) ^ sw) << 3)];
#pragma unroll
            for (int j = 0; j < 4; ++j)
                bv[j] = *(const f16x8*)&Bsh[(wc * 64 + j * 16 + l16) * 64
                                            + (((kc * 4 + quad) ^ sw) << 3)];
#pragma unroll
            for (int i = 0; i < 4; ++i)
#pragma unroll
                for (int j = 0; j < 4; ++j)
                    acc[i][j] = __builtin_amdgcn_mfma_f32_16x16x32_f16(af[i], bv[j], acc[i][j], 0, 0, 0);
        }
    }
    float* dst = (blockIdx.z == 0) ? C : Cp;
    bool addb = (bias != nullptr) && (blockIdx.z == 0);
#pragma unroll
    for (int i = 0; i < 4; ++i)
#pragma unroll
        for (int r = 0; r < 4; ++r) {
            int row = m0 + wr * 64 + i * 16 + quad * 4 + r;
#pragma unroll
            for (int j = 0; j < 4; ++j) {
                int col = n0 + wc * 64 + j * 16 + l16;
                float v = acc[i][j][r];
                if (addb) v += bias[col];
                dst[(size_t)row * N + col] = v;
            }
        }
}

// ---- out += partial (fp32, float4) ----
__global__ void k_reduce(float* __restrict__ out, const float* __restrict__ part, int n4) {
    int i = blockIdx.x * 256 + threadIdx.x;
    if (i >= n4) return;
    float4 a = ((const float4*)out)[i];
    float4 b = ((const float4*)part)[i];
    a.x += b.x; a.y += b.y; a.z += b.z; a.w += b.w;
    ((float4*)out)[i] = a;
}

// ---- RoPE (fp64 angles) -> Qh/Ql (S,3584), Kh (S,512) fp16 ----
// Q is pre-scaled by 1/sqrt(HD) * log2(e): scores come out of QK^T in log2
// domain (softmax via exp2). Yp: optional split-K partial (added pre-rotate).
__global__ void k_rope2(const float* __restrict__ Y, const float* __restrict__ Yp,
                        const int* __restrict__ pos,
                        u16* __restrict__ Qh, u16* __restrict__ Ql,
                        u16* __restrict__ Kh) {
    __shared__ double finv[64];
    int tid = threadIdx.x;
    if (tid < 64)   // inv_freq = theta^(-i/64) = 2^(-i*log2(1e6)/64)
        finv[tid] = exp2(-0.3114307588956902 * (double)tid);
    __syncthreads();
    int s = blockIdx.x;
    double p = (double)pos[s];
    const float* y  = Y + (size_t)s * NQKV;
    const float* yp = Yp ? (Yp + (size_t)s * NQKV) : nullptr;
    const float QSCALE = 0.1275174313f;     // (1/sqrt(128)) * log2(e)
    for (int idx = tid; idx < 4096; idx += 256) {
        int d = idx & 127;
        int i = d & 63;
        double ang = p * finv[i];
        double n = rint(ang * 0.15915494309189535);          // /(2*pi)
        float r = (float)fma(-6.283185307179586, n, ang);    // range-reduced angle
        float sn, cs;
        __sincosf(r, &sn, &cs);
        int idx2 = (d < 64) ? idx + 64 : idx - 64;
        float v  = y[idx];
        float v2 = y[idx2];
        if (yp) { v += yp[idx]; v2 += yp[idx2]; }
        float o  = (d < 64) ? (v * cs - v2 * sn) : (v * cs + v2 * sn);
        if (idx < 3584) {
            u16 hh, ll;
            split2(o * QSCALE, hh, ll);
            Qh[(size_t)s * 3584 + idx] = hh;
            Ql[(size_t)s * 3584 + idx] = ll;
        } else {
            Kh[(size_t)s * 512 + (idx - 3584)] = f2h(o);
        }
    }
}

// ---- transpose V section of Y: (S x 512) fp32 -> Vt (512 x S) fp16 ----
__global__ __launch_bounds__(256) void k_vtrans(const float* __restrict__ Y,
                                                const float* __restrict__ Yp,
                                                u16* __restrict__ Vt) {
    __shared__ __attribute__((aligned(16))) u16 T[64][72];
    int s0 = blockIdx.x * 64, d0 = blockIdx.y * 64;
    int tid = threadIdx.x;
#pragma unroll
    for (int t = 0; t < 16; ++t) {
        int idx = tid + t * 256;
        int r = idx >> 6, c = idx & 63;
        size_t goff = (size_t)(s0 + r) * NQKV + 4096 + d0 + c;
        float val = Y[goff];
        if (Yp) val += Yp[goff];
        T[c][r] = f2h(val);
    }
    __syncthreads();
#pragma unroll
    for (int t = 0; t < 2; ++t) {
        int cc = tid + t * 256;
        int dr = cc >> 3, s8 = (cc & 7) << 3;
        *(u16x8*)(Vt + (size_t)(d0 + dr) * Sq + s0 + s8) = *(const u16x8*)&T[dr][s8];
    }
}

// ---- flash attention fp16: persistent blocks, LPT dynamic queue ----
// Whole items only (R6 lesson: key-splitting was ~neutral - attn is
// throughput-bound, not tail-bound; R5 lesson: in-kernel cross-block merge
// via __threadfence serialized the memory system. Both reverted.)
// LDS: XOR-swizzled power-of-2 tiles (chunk16B ^= row&7), 40960 B total.
// Softmax in log2 domain (Q pre-scaled at RoPE) + T13 defer-max + T5 setprio.
// R3 lesson: no min-waves clamp (forcing VGPR down spills everything).
__global__ __launch_bounds__(256) void k_attn(const u16* __restrict__ Qh,
                                              const u16* __restrict__ Ql,
                                              const u16* __restrict__ Kh,
                                              const u16* __restrict__ Vt,
                                              u16* __restrict__ AO,
                                              int* __restrict__ ctr) {
    __shared__ __attribute__((aligned(16))) u16 Ks[64][128];   // 16384 B, swizzled
    __shared__ __attribute__((aligned(16))) u16 Vs[128][64];   // 16384 B, swizzled
    __shared__ __attribute__((aligned(16))) u16 Ps[4][16][64]; //  8192 B, swizzled

    int tid = threadIdx.x;
    int wave = tid >> 6, lane = tid & 63, l16 = lane & 15, quad = lane >> 4;
    int sw = l16 & 7;                       // read-side swizzle key (= row&7)

    for (;;) {
        __syncthreads();                   // all waves done with prior item
        if (tid == 0) *(int*)&Ks[0][0] = atomicAdd(ctr, 1);
        __syncthreads();
        int item = *(const int*)&Ks[0][0];
        if (item >= 32 * NH) break;        // block-uniform exit
        int qt = 31 - item / NH;           // longest first (LPT)
        int h  = item % NH;
        int q0 = qt * 64;
        int kvh = h / 7;                   // NH/NKV = 7
        __syncthreads();                   // item slot read by all before staging

        const u16* Kbase = Kh + kvh * HD;                  // row stride 512
        const u16* Vbase = Vt + (size_t)(kvh * HD) * Sq;   // row stride Sq

        // Q fragments hi/lo direct from global (A-layout: m=l16, k=quad*8+j)
        f16x8 qfh[4], qfl[4];
        {
            size_t qoff = (size_t)(q0 + wave * 16 + l16) * Hdim + h * HD + quad * 8;
#pragma unroll
            for (int kc = 0; kc < 4; ++kc) {
                qfh[kc] = *(const f16x8*)(Qh + qoff + kc * 32);
                qfl[kc] = *(const f16x8*)(Ql + qoff + kc * 32);
            }
        }

        // initial staging of tile 0 (swizzled writes)
#pragma unroll
        for (int t = 0; t < 4; ++t) {
            int c = tid + t * 256;
            int row = c >> 4, ch = (c & 15) ^ (row & 7);
            *(u16x8*)&Ks[row][ch << 3] = *(const u16x8*)(Kbase + (size_t)row * 512 + ((c & 15) << 3));
        }
#pragma unroll
        for (int t = 0; t < 4; ++t) {
            int c = tid + t * 256;
            int d = c >> 3, ch = (c & 7) ^ (d & 7);
            *(u16x8*)&Vs[d][ch << 3] = *(const u16x8*)(Vbase + (size_t)d * Sq + ((c & 7) << 3));
        }
        __syncthreads();

        f32x4 O[8];
        f32x4 zero4 = {0.f, 0.f, 0.f, 0.f};
#pragma unroll
        for (int t = 0; t < 8; ++t) O[t] = zero4;
        float mrow[4], lrow[4];
#pragma unroll
        for (int r = 0; r < 4; ++r) { mrow[r] = -1e30f; lrow[r] = 0.f; }

        for (int kt = 0; kt <= qt; ++kt) {
            int k0 = kt * 64;
            int kn = (kt < qt) ? k0 + 64 : k0;     // clamped prefetch base

            // ---- issue next-tile loads into registers (latency overlapped) ----
            u16x8 nk[4], nv[4];
#pragma unroll
            for (int t = 0; t < 4; ++t) {
                int c = tid + t * 256;
                nk[t] = *(const u16x8*)(Kbase + (size_t)(kn + (c >> 4)) * 512 + ((c & 15) << 3));
                nv[t] = *(const u16x8*)(Vbase + (size_t)(c >> 3) * Sq + kn + ((c & 7) << 3));
            }

            // ---- compute current tile from LDS (log2-domain scores) ----
            f32x4 sa[4];                       // S = Q K^T, 2-term split
            __builtin_amdgcn_s_setprio(1);
#pragma unroll
            for (int ct = 0; ct < 4; ++ct) {
                f32x4 z = zero4;
#pragma unroll
                for (int kc = 0; kc < 4; ++kc) {
                    f16x8 b = *(const f16x8*)&Ks[ct * 16 + l16][(((kc * 4 + quad) ^ sw)) << 3];
                    z = __builtin_amdgcn_mfma_f32_16x16x32_f16(qfh[kc], b, z, 0, 0, 0);
                    z = __builtin_amdgcn_mfma_f32_16x16x32_f16(qfl[kc], b, z, 0, 0, 0);
                }
                sa[ct] = z;
            }
            __builtin_amdgcn_s_setprio(0);
            if (kt == qt) {
#pragma unroll
                for (int ct = 0; ct < 4; ++ct)
#pragma unroll
                    for (int r = 0; r < 4; ++r)
                        if (k0 + ct * 16 + l16 > q0 + wave * 16 + quad * 4 + r) sa[ct][r] = -1e30f;
            }
            // row max of this tile
            float pmax[4];
#pragma unroll
            for (int r = 0; r < 4; ++r) {
                float mx = fmaxf(fmaxf(sa[0][r], sa[1][r]), fmaxf(sa[2][r], sa[3][r]));
#pragma unroll
                for (int off = 1; off < 16; off <<= 1)
                    mx = fmaxf(mx, __shfl_xor(mx, off, 64));
                pmax[r] = mx;
            }
            // T13 defer-max: skip rescale while max growth <= 8 (P <= 2^8)
            bool keep = (pmax[0] <= mrow[0] + 8.f) && (pmax[1] <= mrow[1] + 8.f) &&
                        (pmax[2] <= mrow[2] + 8.f) && (pmax[3] <= mrow[3] + 8.f);
            if (!__all(keep)) {
#pragma unroll
                for (int r = 0; r < 4; ++r) {
                    float mnew = fmaxf(mrow[r], pmax[r]);
                    float alpha = exp2f(mrow[r] - mnew);
                    mrow[r] = mnew;
                    lrow[r] *= alpha;
#pragma unroll
                    for (int ct = 0; ct < 8; ++ct) O[ct][r] *= alpha;
                }
            }
            float rs[4] = {0.f, 0.f, 0.f, 0.f};
#pragma unroll
            for (int ct = 0; ct < 4; ++ct)
#pragma unroll
                for (int r = 0; r < 4; ++r) {
                    float p = exp2f(sa[ct][r] - mrow[r]);
                    rs[r] += p;
                    // swizzled Ps write: chunk ^= row&7, row = quad*4+r
                    Ps[wave][quad * 4 + r][(ct * 16 + l16) ^ (((quad * 4 + r) & 7) << 3)] = f2h(p);
                }
#pragma unroll
            for (int r = 0; r < 4; ++r) {
#pragma unroll
                for (int off = 1; off < 16; off <<= 1)
                    rs[r] += __shfl_xor(rs[r], off, 64);
                lrow[r] += rs[r];
            }
            __builtin_amdgcn_s_setprio(1);
#pragma unroll
            for (int kc = 0; kc < 2; ++kc) {   // PV from LDS (Ps wave-private)
                f16x8 a = *(const f16x8*)&Ps[wave][l16][(((kc * 4 + quad) ^ sw)) << 3];
#pragma unroll
                for (int ct = 0; ct < 8; ++ct) {
                    f16x8 b = *(const f16x8*)&Vs[ct * 16 + l16][(((kc * 4 + quad) ^ sw)) << 3];
                    O[ct] = __builtin_amdgcn_mfma_f32_16x16x32_f16(a, b, O[ct], 0, 0, 0);
                }
            }
            __builtin_amdgcn_s_setprio(0);

            // ---- commit prefetched tile to LDS (swizzled) ----
            __syncthreads();                   // all waves done reading Ks/Vs
#pragma unroll
            for (int t = 0; t < 4; ++t) {
                int c = tid + t * 256;
                int row = c >> 4, chk = ((c & 15) ^ (row & 7));
                int d = c >> 3, chv = ((c & 7) ^ (d & 7));
                *(u16x8*)&Ks[row][chk << 3] = nk[t];
                *(u16x8*)&Vs[d][chv << 3]   = nv[t];
            }
            __syncthreads();                   // staged data visible
        }
#pragma unroll
        for (int r = 0; r < 4; ++r) {
            float inv = 1.f / lrow[r];
            int row = q0 + wave * 16 + quad * 4 + r;
#pragma unroll
            for (int ct = 0; ct < 8; ++ct)
                AO[(size_t)row * 3584 + h * HD + ct * 16 + l16] = f2h(O[ct][r] * inv);
        }
    }
}

extern "C" void kernel_launch(void* const* d_in, const int* in_sizes, int n_in,
                              void* d_out, int out_size, void* d_ws, size_t ws_size,
                              hipStream_t stream) {
    (void)in_sizes; (void)n_in; (void)out_size;
    const float* hidden = (const float*)d_in[0];
    const int*   pos    = (const int*)d_in[1];
    const int*   qw_q = (const int*)d_in[2];
    const int*   qz_q = (const int*)d_in[3];
    const float* sc_q = (const float*)d_in[4];
    const float* b_q  = (const float*)d_in[5];
    const int*   qw_k = (const int*)d_in[6];
    const int*   qz_k = (const int*)d_in[7];
    const float* sc_k = (const float*)d_in[8];
    const float* b_k  = (const float*)d_in[9];
    const int*   qw_v = (const int*)d_in[10];
    const int*   qz_v = (const int*)d_in[11];
    const float* sc_v = (const float*)d_in[12];
    const float* b_v  = (const float*)d_in[13];
    const int*   qw_o = (const int*)d_in[14];
    const int*   qz_o = (const int*)d_in[15];
    const float* sc_o = (const float*)d_in[16];
    float* out = (float*)d_out;

    char* base = (char*)d_ws;
    size_t off = 0;
    auto alloc = [&](size_t bytes) {
        char* p = base + off;
        off += (bytes + 255) & ~(size_t)255;
        return p;
    };
    u16* Wh = (u16*)alloc((size_t)NQKV * KD * 2);   // 33.0 MB (reused for W_o)
    u16* Xh = (u16*)alloc((size_t)Sq * Hdim * 2);   // 14.7 MB (reused as Qh, then partial)
    u16* Xl = (u16*)alloc((size_t)Sq * Hdim * 2);   // 14.7 MB (Ql, then partial)
    float* Y = (float*)alloc((size_t)Sq * NQKV * 4);// 37.7 MB (reused for AO)
    u16* Khb = (u16*)alloc((size_t)Sq * 512 * 2);   //  2.1 MB
    u16* Vt  = (u16*)alloc((size_t)512 * Sq * 2);   //  2.1 MB
    float* biasc = (float*)alloc(NQKV * 4);
    int*   ctr   = (int*)alloc(4096);               // attn work-queue counter
    // split-K partial for GEMM1 (live GEMM1 -> rope/vtrans); gated on ws_size
    float* Part1 = (float*)alloc((size_t)Sq * NQKV * 4);   // 37.7 MB
    bool deep = (off <= ws_size);
    u16* Qhb = Xh;                 // Xh dead after GEMM1
    u16* Qlb = Xl;
    u16* AO  = (u16*)Y;            // Y dead after rope/vtrans
    u16* Wo  = Wh;                 // Wh dead after GEMM1
    float* Part = (float*)Xh;      // Xh+Xl contiguous = 29.4 MB, dead after attn

    hipMemsetAsync(ctr, 0, 4096, stream);           // ws is re-poisoned each call
    k_cvt<<<3584, 256, 0, stream>>>(hidden, Xh, (Sq * Hdim) / 8);
    k_bias<<<18, 256, 0, stream>>>(b_q, b_k, b_v, biasc);
    k_dequant<<<dim3(3584 / 64, KD / 64), 256, 0, stream>>>(qw_q, qz_q, sc_q, Wh, 3584);
    k_dequant<<<dim3(512 / 64, KD / 64), 256, 0, stream>>>(qw_k, qz_k, sc_k, Wh + (size_t)3584 * KD, 512);
    k_dequant<<<dim3(512 / 64, KD / 64), 256, 0, stream>>>(qw_v, qz_v, sc_v, Wh + (size_t)4096 * KD, 512);
    // GEMM1: split-K=2 -> 1152 blocks = 4.5/CU; partial folded into rope/vtrans.
    if (deep) {
        k_gemm_f16<<<dim3(NQKV / 128, Sq / 128, 2), 256, 0, stream>>>(Xh, Wh, biasc, Y, Part1, Sq, NQKV, KD);
    } else {
        k_gemm_f16<<<dim3(NQKV / 128, Sq / 128, 1), 256, 0, stream>>>(Xh, Wh, biasc, Y, nullptr, Sq, NQKV, KD);
    }
    k_rope2<<<Sq, 256, 0, stream>>>(Y, deep ? Part1 : nullptr, pos, Qhb, Qlb, Khb);
    k_vtrans<<<dim3(Sq / 64, 512 / 64), 256, 0, stream>>>(Y, deep ? Part1 : nullptr, Vt);
    k_dequant<<<dim3(3584 / 64, KD / 64), 256, 0, stream>>>(qw_o, qz_o, sc_o, Wo, 3584);
    k_attn<<<dim3(1024), 256, 0, stream>>>(Qhb, Qlb, Khb, Vt, AO, ctr);
    k_gemm_f16<<<dim3(Hdim / 128, Sq / 128, 2), 256, 0, stream>>>(AO, Wo, nullptr, out, Part, Sq, Hdim, KD);
    k_reduce<<<(Sq * Hdim / 4 + 255) / 256, 256, 0, stream>>>(out, Part, Sq * Hdim / 4);
}